// Round 4
// baseline (265.553 us; speedup 1.0000x reference)
//
#include <hip/hip_runtime.h>

// ARIMA flow sampling, R17 = dual-batch WG (ILP fix).
// Post-mortem R16: stagger neutral (208.9us) -> co-resident-WG lockstep is
// NOT the limiter. Measured issue work per wave per step ~1100cy vs wall
// 4950cy: 78% dependency stall (barrier -> ds_read -> 4-deep MFMA chain ->
// 14-deep tanh chain -> pack -> barrier, x2/step). Matches prior session's
// "dependency chain is the floor" conclusion. Fix = more independent work
// per wave: each WG now carries TWO batches (grid 512, b=2*blk, 2*blk+1)
// through the IDENTICAL two-barrier skeleton (no new sync structure, unlike
// the R12 cross-wave pairing that raced). Weights shared; z/v/h2s/acc
// duplicated. Per-CU pipe demand unchanged; wall should drop from
// chain-bound ~4950cy/step toward pipe-bound ~2600cy/step.
// Predicted: main 206 -> 120-150us, VALUBusy 52 -> 75-90, MfmaUtil 23 -> ~37,
// Occupancy ~25% (8 waves/CU), LDS 17408, absmax exactly 0.0078125.
//
// Algebra (unchanged):
//   z_s := W1'[x_s, t_s, 1]  (L1 preact, fp32 in MFMA accumulators)
//   h1 = tanh(z); h2 = tanh(W2'[h1,1])           (GEMM 1)
//   z += dtM @ h2 + v        dtM = dt*W1x@W3     (GEMM 2, acc_in = z)
//   x_100 = W3'[dt*sum_s h2_s, 1]                (x_0 cancels: 100*dt == 1)
// v = sv - dt*z_0 per-row in regs; t folded into v; biases as input feats.

#define NB 1024
#define NQ 96
#define NC 16
#define NH 100
#define QP1 97
#define QP2 98
#define NTHR 256
#define STR 136
#define NSTEPS_ 100
#define MT_K 128  // dtM row stride (bf16)

typedef __attribute__((ext_vector_type(8))) short bf16x8;
typedef __attribute__((ext_vector_type(4))) float f32x4;
typedef __attribute__((ext_vector_type(2))) float f32x2;
typedef __attribute__((ext_vector_type(2))) unsigned uintx2;

#define LO2(v) __builtin_shufflevector(v, v, 0, 1)
#define HI2(v) __builtin_shufflevector(v, v, 2, 3)

__device__ __forceinline__ f32x4 splat4(float f) {
  f32x4 v = f;
  return v;
}

__device__ __forceinline__ f32x2 splat2(float f) {
  f32x2 v = f;
  return v;
}

__device__ __forceinline__ short f2bf_rne(float f) {  // one-time paths only
  unsigned u = __builtin_bit_cast(unsigned, f);
  u = u + 0x7fffu + ((u >> 16) & 1u);
  return (short)(u >> 16);
}

// 2 floats -> packed bf16x2 dword, RNE, single instruction.
__device__ __forceinline__ unsigned cvtpk_bf16(float a, float b) {
  unsigned r;
  asm("v_cvt_pk_bf16_f32 %0, %1, %2" : "=v"(r) : "v"(a), "v"(b));
  return r;
}

// Pade(5,4) tanh on two f32x2 pairs (= one f32x4 tile).
__device__ __forceinline__ void tanh_pair(f32x2& p, f32x2& q) {
  f32x2 up = p * p, uq = q * q;
  f32x2 np = p * __builtin_elementwise_fma(up + splat2(105.0f), up, splat2(945.0f));
  f32x2 nq = q * __builtin_elementwise_fma(uq + splat2(105.0f), uq, splat2(945.0f));
  f32x2 dp = __builtin_elementwise_fma(
      __builtin_elementwise_fma(splat2(15.0f), up, splat2(420.0f)), up,
      splat2(945.0f));
  f32x2 dq = __builtin_elementwise_fma(
      __builtin_elementwise_fma(splat2(15.0f), uq, splat2(420.0f)), uq,
      splat2(945.0f));
  f32x2 rp, rq;
  rp[0] = __builtin_amdgcn_rcpf(dp[0]);
  rp[1] = __builtin_amdgcn_rcpf(dp[1]);
  rq[0] = __builtin_amdgcn_rcpf(dq[0]);
  rq[1] = __builtin_amdgcn_rcpf(dq[1]);
  f32x2 vp = np * rp, vq = nq * rq;
  p = __builtin_elementwise_min(
      __builtin_elementwise_max(vp, splat2(-1.0f)), splat2(1.0f));
  q = __builtin_elementwise_min(
      __builtin_elementwise_max(vq, splat2(-1.0f)), splat2(1.0f));
}

// ---------------- prep: dtM = dt * W1x @ W3 (bf16) + s-vec ----------------
// grid 128 (= n), block 512 (k = tid&127, jslice = tid>>7); LDS reduce.
__global__ void __launch_bounds__(512) arima_prep(
    const float* __restrict__ W1, const float* __restrict__ b1,
    const float* __restrict__ W3, const float* __restrict__ b3,
    short* __restrict__ Mt, float* __restrict__ sv) {
  __shared__ float part[4][128];
  __shared__ float pb[128];
  const int n = blockIdx.x;
  const int tid = threadIdx.x;
  const int k = tid & 127, js = tid >> 7;
  float s = 0.0f;
  if (n < NH && k < NH) {
    int j0 = js * 25, j1 = (js == 3) ? QP1 : j0 + 25;
    for (int j = j0; j < j1; ++j)
      s = fmaf(W1[n * QP2 + j], W3[j * NH + k], s);
  }
  part[js][k] = s;
  if (tid < 128)
    pb[tid] = (tid < QP1 && n < NH) ? W1[n * QP2 + tid] * b3[tid] : 0.0f;
  __syncthreads();
  if (js == 0) {
    float tot = part[0][k] + part[1][k] + part[2][k] + part[3][k];
    Mt[n * MT_K + k] = f2bf_rne(0.01f * tot);
  }
  if (tid == 0) {
    float d = 0.0f;
    for (int j = 0; j < 128; ++j) d += pb[j];
    sv[n] = (n < NH) ? 0.01f * (d + b1[n] + W1[n * QP2 + QP1]) : 0.0f;
  }
}

// ---------------- main ----------------
// Weight A-frag from fp32 W: lane holds W'[m][k], k<KW -> W, k==KW -> bias.
__device__ void load_afrag(const float* __restrict__ W,
                           const float* __restrict__ bias, int ws, int mvalid,
                           int KW, int m, int quad, bf16x8 dst[4]) {
#pragma unroll
  for (int kb = 0; kb < 4; ++kb) {
    bf16x8 v;
#pragma unroll
    for (int i = 0; i < 8; ++i) {
      int k = kb * 32 + quad * 8 + i;
      float f = 0.0f;
      if (m < mvalid) {
        if (k < KW) f = W[m * ws + k];
        else if (k == KW) f = bias[m];
      }
      v[i] = f2bf_rne(f);
    }
    dst[kb] = v;
  }
}

// acc += A * B(LDS). 2 tiles, K=128 (4 kb). acc carries in (z-update!).
__device__ __forceinline__ void gemm_acc(const short* __restrict__ src,
                                         int rbase, const bf16x8 (&A)[2][4],
                                         f32x4 (&acc)[2]) {
#pragma unroll
  for (int kb = 0; kb < 4; ++kb) {
    bf16x8 bv = *(const bf16x8*)(src + rbase + kb * 32);  // 16B aligned
    acc[0] = __builtin_amdgcn_mfma_f32_16x16x32_bf16(A[0][kb], bv, acc[0], 0, 0, 0);
    acc[1] = __builtin_amdgcn_mfma_f32_16x16x32_bf16(A[1][kb], bv, acc[1], 0, 0, 0);
  }
}

// cvt_pk + b64-store both tiles to [row][feat] layout.
__device__ __forceinline__ void write_tiles2(short* __restrict__ dst, int wrow,
                                             int T0, int quad, f32x2 a0,
                                             f32x2 a1, f32x2 b0, f32x2 b1) {
  uintx2 a, b;
  a.x = cvtpk_bf16(a0[0], a0[1]);
  a.y = cvtpk_bf16(a1[0], a1[1]);
  b.x = cvtpk_bf16(b0[0], b0[1]);
  b.y = cvtpk_bf16(b1[0], b1[1]);
  *(uintx2*)(dst + wrow + T0 * 16 + quad * 4) = a;
  *(uintx2*)(dst + wrow + (T0 + 1) * 16 + quad * 4) = b;
}

__global__ void __launch_bounds__(NTHR, 2)
arima_r17(const float* __restrict__ series,
          const float* __restrict__ rand_error, const float* __restrict__ W1,
          const float* __restrict__ b1, const float* __restrict__ W2,
          const float* __restrict__ b2, const float* __restrict__ W3,
          const float* __restrict__ b3, const short* __restrict__ Mt,
          const float* __restrict__ sv, float* __restrict__ out) {
  // [p] = sub-batch 0/1. Same two-barrier ping-pong as R13/R15.
  __shared__ __align__(16) short buf1[2][16 * STR];  // h1 (feat 100 = 1.0)
  __shared__ __align__(16) short buf2[2][16 * STR];  // x0 / h2 / H2avg

  const int tid = threadIdx.x;
  const int w = tid >> 6, l = tid & 63;
  const int col = l & 15, quad = l >> 4;  // col = channel = data row
  const int b0 = blockIdx.x * 2;          // WG = two batches (b0, b0+1)
  const int T0 = 2 * w;                   // uniform: wave owns tiles 2w,2w+1
  const int wrow = col * STR;
  const int rbase = wrow + quad * 8;
  const bool fixw = (w == 3 && quad == 1);  // owns feat 100 (tile 6, reg 0)

  // ---- x0 -> buf2[p] : feats [x0(97), t0=0, 1, 0...] ----
#pragma unroll
  for (int p = 0; p < 2; ++p) {
    f32x4 xv[2];
#pragma unroll
    for (int t = 0; t < 2; ++t)
#pragma unroll
      for (int r = 0; r < 4; ++r) {
        int q = (T0 + t) * 16 + quad * 4 + r;
        float f = 0.0f;
        if (q < NQ) f = series[((b0 + p) * NQ + q) * NC + col];
        else if (q == NQ) f = rand_error[(b0 + p) * NC + col];
        else if (q == QP2) f = 1.0f;  // bias feature (q==97: t0 = 0)
        xv[t][r] = f;
      }
    write_tiles2(buf2[p], wrow, T0, quad, LO2(xv[0]), HI2(xv[0]), LO2(xv[1]),
                 HI2(xv[1]));
  }
  __syncthreads();

  // ---- z0 = W1'[x0,0,1] ; v = sv - dt*z0 ; h1_0 -> buf1 ----
  f32x4 z[2][2], v[2][2];
  {
    bf16x8 a1[2][4];  // transient, shared across batches
#pragma unroll
    for (int t = 0; t < 2; ++t)
      load_afrag(W1, b1, QP2, NH, QP2, (T0 + t) * 16 + col, quad, a1[t]);
    f32x4 s[2];
#pragma unroll
    for (int t = 0; t < 2; ++t)
#pragma unroll
      for (int r = 0; r < 4; ++r) s[t][r] = sv[(T0 + t) * 16 + quad * 4 + r];
#pragma unroll
    for (int p = 0; p < 2; ++p) {
      z[p][0] = splat4(0.0f);
      z[p][1] = splat4(0.0f);
      gemm_acc(buf2[p], rbase, a1, z[p]);
#pragma unroll
      for (int t = 0; t < 2; ++t) v[p][t] = s[t] - splat4(0.01f) * z[p][t];
    }
  }
#pragma unroll
  for (int p = 0; p < 2; ++p) {
    f32x2 p0 = LO2(z[p][0]), p1 = HI2(z[p][0]), p2 = LO2(z[p][1]),
          p3 = HI2(z[p][1]);
    tanh_pair(p0, p1);
    tanh_pair(p2, p3);
    if (fixw) p0[0] = 1.0f;  // h1 feat 100 = 1.0 (W2 bias input)
    write_tiles2(buf1[p], wrow, T0, quad, p0, p1, p2, p3);
  }
  __syncthreads();

  // ---- persistent frags: W2' + dtM (shared across both batches) ----
  bf16x8 a2[2][4], am[2][4];
#pragma unroll
  for (int t = 0; t < 2; ++t) {
    load_afrag(W2, b2, NH, NH, NH, (T0 + t) * 16 + col, quad, a2[t]);
#pragma unroll
    for (int kb = 0; kb < 4; ++kb)
      am[t][kb] = *(const bf16x8*)(Mt + ((T0 + t) * 16 + col) * MT_K +
                                   kb * 32 + quad * 8);
  }
  f32x2 h2s[2][2][2];
#pragma unroll
  for (int p = 0; p < 2; ++p)
#pragma unroll
    for (int t = 0; t < 2; ++t)
#pragma unroll
      for (int h = 0; h < 2; ++h) h2s[p][t][h] = splat2(0.0f);

#pragma unroll 1
  for (int step = 0; step < NSTEPS_; ++step) {
    // GEMM 1 (both batches): h2 = tanh(W2'[h1,1]); store; accumulate H2sum.
    f32x4 acc[2][2];
#pragma unroll
    for (int p = 0; p < 2; ++p) {
      acc[p][0] = splat4(0.0f);
      acc[p][1] = splat4(0.0f);
      gemm_acc(buf1[p], rbase, a2, acc[p]);
    }
#pragma unroll
    for (int p = 0; p < 2; ++p) {
      f32x2 p0 = LO2(acc[p][0]), p1 = HI2(acc[p][0]), p2 = LO2(acc[p][1]),
            p3 = HI2(acc[p][1]);
      tanh_pair(p0, p1);
      tanh_pair(p2, p3);
      write_tiles2(buf2[p], wrow, T0, quad, p0, p1, p2, p3);
      h2s[p][0][0] = h2s[p][0][0] + p0;
      h2s[p][0][1] = h2s[p][0][1] + p1;
      h2s[p][1][0] = h2s[p][1][0] + p2;
      h2s[p][1][1] = h2s[p][1][1] + p3;
    }
    __syncthreads();
    // GEMM 2 (both): z += dtM h2 (acc_in = z!), z += v ; h1' = tanh -> buf1
#pragma unroll
    for (int p = 0; p < 2; ++p) gemm_acc(buf2[p], rbase, am, z[p]);
#pragma unroll
    for (int p = 0; p < 2; ++p) {
      z[p][0] = z[p][0] + v[p][0];
      z[p][1] = z[p][1] + v[p][1];
      f32x2 q0 = LO2(z[p][0]), q1 = HI2(z[p][0]), q2 = LO2(z[p][1]),
            q3 = HI2(z[p][1]);
      tanh_pair(q0, q1);
      tanh_pair(q2, q3);
      if (fixw) q0[0] = 1.0f;
      write_tiles2(buf1[p], wrow, T0, quad, q0, q1, q2, q3);
    }
    __syncthreads();
  }

  // ---- out = W3'[dt*H2sum, 1] ----
#pragma unroll
  for (int p = 0; p < 2; ++p) {
    f32x2 ha00 = splat2(0.01f) * h2s[p][0][0];
    f32x2 ha01 = splat2(0.01f) * h2s[p][0][1];
    f32x2 ha10 = splat2(0.01f) * h2s[p][1][0];
    f32x2 ha11 = splat2(0.01f) * h2s[p][1][1];
    if (fixw) ha00[0] = 1.0f;  // bias feature for b3
    write_tiles2(buf2[p], wrow, T0, quad, ha00, ha01, ha10, ha11);
  }
  __syncthreads();
  {
    bf16x8 a3[2][4];
#pragma unroll
    for (int t = 0; t < 2; ++t)
      load_afrag(W3, b3, NH, QP1, NH, (T0 + t) * 16 + col, quad, a3[t]);
#pragma unroll
    for (int p = 0; p < 2; ++p) {
      f32x4 o[2];
      o[0] = splat4(0.0f);
      o[1] = splat4(0.0f);
      gemm_acc(buf2[p], rbase, a3, o);
#pragma unroll
      for (int t = 0; t < 2; ++t)
#pragma unroll
        for (int r = 0; r < 4; ++r) {
          int q = (T0 + t) * 16 + quad * 4 + r;
          if (q < QP1) out[((b0 + p) * QP1 + q) * NC + col] = o[t][r];
        }
    }
  }
}

extern "C" void kernel_launch(void* const* d_in, const int* in_sizes, int n_in,
                              void* d_out, int out_size, void* d_ws,
                              size_t ws_size, hipStream_t stream) {
  const float* series = (const float*)d_in[0];
  const float* rand_error = (const float*)d_in[1];
  const float* W1 = (const float*)d_in[2];
  const float* b1 = (const float*)d_in[3];
  const float* W2 = (const float*)d_in[4];
  const float* b2 = (const float*)d_in[5];
  const float* W3 = (const float*)d_in[6];
  const float* b3 = (const float*)d_in[7];
  float* out = (float*)d_out;

  short* Mt = (short*)d_ws;                             // 128*128*2 = 32768 B
  float* sv = (float*)((char*)d_ws + MT_K * MT_K * 2);  // 128 f32

  hipLaunchKernelGGL(arima_prep, dim3(128), dim3(512), 0, stream, W1, b1, W3,
                     b3, Mt, sv);
  hipLaunchKernelGGL(arima_r17, dim3(NB / 2), dim3(NTHR), 0, stream, series,
                     rand_error, W1, b1, W2, b2, W3, b3, Mt, sv, out);
}

// Round 6
// 255.406 us; speedup vs baseline: 1.0397x; 1.0397x over previous
//
#include <hip/hip_runtime.h>

// ARIMA flow sampling, R19 = R18 resubmit (round 5 was an infra failure:
// "MI355X container failed twice" — kernel never compiled/ran).
// R18 = R15 + pi-permuted LDS layout (b128 writes).
// Post-mortems: R16 stagger NEUTRAL (lockstep not limiter), R17 dual-batch
// NEUTRAL (ILP redundant with 4-waves/SIMD TLP; VALU cyc/CU-step invariant
// ~2550). Pipe audit: LDS is co-dominant (~192 instr + 777 measured conflict
// cyc/CU-step, 4.05/instr invariant). Reads are optimal-class; writes are
// fixable: permute feature storage order pi(p = 32w + 8q + 4t + r) so each
// lane's 8 outputs are CONTIGUOUS -> one aligned ds_write_b128 replaces two
// ds_write_b64 (write instrs halved). pi is absorbed at weight-frag fill
// (load_afrag / Mt gather permuted columns, one-time register work); the
// K-loop read code is byte-identical. Arithmetic bit-identical.
// Predicted: BANK_CONFLICT 1.99e7 -> ~1.2e7, main 206 -> 185-195us,
// VALUBusy -> ~56, absmax exactly 0.0078125. Conflicts flat => read-side
// structural => pivot to tanh element-work reduction next.
//
// Algebra (unchanged):
//   z_s := W1'[x_s, t_s, 1]  (L1 preact, fp32 in MFMA accumulators)
//   h1 = tanh(z); h2 = tanh(W2'[h1,1])           (GEMM 1)
//   z += dtM @ h2 + v        dtM = dt*W1x@W3     (GEMM 2, acc_in = z)
//   x_100 = W3'[dt*sum_s h2_s, 1]                (x_0 cancels: 100*dt == 1)
// v = sv - dt*z_0 per-row in regs; t folded into v; biases as input feats.
// pi storage: position p = 32w + 8q + 4t + r holds feature
// f(p) = 32*(p>>5) + 16*((p>>2)&1) + 4*((p>>3)&3) + (p&3).

#define NB 1024
#define NQ 96
#define NC 16
#define NH 100
#define QP1 97
#define QP2 98
#define NTHR 256
#define STR 136
#define NSTEPS_ 100
#define MT_K 128  // dtM row stride (bf16)

typedef __attribute__((ext_vector_type(8))) short bf16x8;
typedef __attribute__((ext_vector_type(4))) short shortx4;
typedef __attribute__((ext_vector_type(4))) float f32x4;
typedef __attribute__((ext_vector_type(2))) float f32x2;
typedef __attribute__((ext_vector_type(4))) unsigned uintx4;

#define LO2(v) __builtin_shufflevector(v, v, 0, 1)
#define HI2(v) __builtin_shufflevector(v, v, 2, 3)

__device__ __forceinline__ f32x4 splat4(float f) {
  f32x4 v = f;
  return v;
}

__device__ __forceinline__ f32x2 splat2(float f) {
  f32x2 v = f;
  return v;
}

__device__ __forceinline__ short f2bf_rne(float f) {  // one-time paths only
  unsigned u = __builtin_bit_cast(unsigned, f);
  u = u + 0x7fffu + ((u >> 16) & 1u);
  return (short)(u >> 16);
}

// 2 floats -> packed bf16x2 dword, RNE, single instruction.
__device__ __forceinline__ unsigned cvtpk_bf16(float a, float b) {
  unsigned r;
  asm("v_cvt_pk_bf16_f32 %0, %1, %2" : "=v"(r) : "v"(a), "v"(b));
  return r;
}

// Pade(5,4) tanh on two f32x2 pairs (= one f32x4 tile).
__device__ __forceinline__ void tanh_pair(f32x2& p, f32x2& q) {
  f32x2 up = p * p, uq = q * q;
  f32x2 np = p * __builtin_elementwise_fma(up + splat2(105.0f), up, splat2(945.0f));
  f32x2 nq = q * __builtin_elementwise_fma(uq + splat2(105.0f), uq, splat2(945.0f));
  f32x2 dp = __builtin_elementwise_fma(
      __builtin_elementwise_fma(splat2(15.0f), up, splat2(420.0f)), up,
      splat2(945.0f));
  f32x2 dq = __builtin_elementwise_fma(
      __builtin_elementwise_fma(splat2(15.0f), uq, splat2(420.0f)), uq,
      splat2(945.0f));
  f32x2 rp, rq;
  rp[0] = __builtin_amdgcn_rcpf(dp[0]);
  rp[1] = __builtin_amdgcn_rcpf(dp[1]);
  rq[0] = __builtin_amdgcn_rcpf(dq[0]);
  rq[1] = __builtin_amdgcn_rcpf(dq[1]);
  f32x2 vp = np * rp, vq = nq * rq;
  p = __builtin_elementwise_min(
      __builtin_elementwise_max(vp, splat2(-1.0f)), splat2(1.0f));
  q = __builtin_elementwise_min(
      __builtin_elementwise_max(vq, splat2(-1.0f)), splat2(1.0f));
}

// ---------------- prep: dtM = dt * W1x @ W3 (bf16) + s-vec ----------------
// grid 128 (= n), block 512 (k = tid&127, jslice = tid>>7); LDS reduce.
// Mt stays in ORIGINAL k order; pi applied at am-fragment fill in main.
__global__ void __launch_bounds__(512) arima_prep(
    const float* __restrict__ W1, const float* __restrict__ b1,
    const float* __restrict__ W3, const float* __restrict__ b3,
    short* __restrict__ Mt, float* __restrict__ sv) {
  __shared__ float part[4][128];
  __shared__ float pb[128];
  const int n = blockIdx.x;
  const int tid = threadIdx.x;
  const int k = tid & 127, js = tid >> 7;
  float s = 0.0f;
  if (n < NH && k < NH) {
    int j0 = js * 25, j1 = (js == 3) ? QP1 : j0 + 25;
    for (int j = j0; j < j1; ++j)
      s = fmaf(W1[n * QP2 + j], W3[j * NH + k], s);
  }
  part[js][k] = s;
  if (tid < 128)
    pb[tid] = (tid < QP1 && n < NH) ? W1[n * QP2 + tid] * b3[tid] : 0.0f;
  __syncthreads();
  if (js == 0) {
    float tot = part[0][k] + part[1][k] + part[2][k] + part[3][k];
    Mt[n * MT_K + k] = f2bf_rne(0.01f * tot);
  }
  if (tid == 0) {
    float d = 0.0f;
    for (int j = 0; j < 128; ++j) d += pb[j];
    sv[n] = (n < NH) ? 0.01f * (d + b1[n] + W1[n * QP2 + QP1]) : 0.0f;
  }
}

// ---------------- main ----------------
// Weight A-frag from fp32 W, pi-permuted k columns:
// frag slot (kb, i) holds W column kcol = kb*32 + 16*(i>>2) + quad*4 + (i&3).
__device__ void load_afrag(const float* __restrict__ W,
                           const float* __restrict__ bias, int ws, int mvalid,
                           int KW, int m, int quad, bf16x8 dst[4]) {
#pragma unroll
  for (int kb = 0; kb < 4; ++kb) {
    bf16x8 v;
#pragma unroll
    for (int i = 0; i < 8; ++i) {
      int kcol = kb * 32 + ((i >> 2) << 4) + quad * 4 + (i & 3);
      float f = 0.0f;
      if (m < mvalid) {
        if (kcol < KW) f = W[m * ws + kcol];
        else if (kcol == KW) f = bias[m];
      }
      v[i] = f2bf_rne(f);
    }
    dst[kb] = v;
  }
}

// acc += A * B(LDS). 2 tiles, K=128 (4 kb). acc carries in (z-update!).
// Read code identical to R15; k index is now storage (pi) order.
__device__ __forceinline__ void gemm_acc(const short* __restrict__ src,
                                         int rbase, const bf16x8 (&A)[2][4],
                                         f32x4 (&acc)[2]) {
#pragma unroll
  for (int kb = 0; kb < 4; ++kb) {
    bf16x8 bv = *(const bf16x8*)(src + rbase + kb * 32);  // 16B aligned
    acc[0] = __builtin_amdgcn_mfma_f32_16x16x32_bf16(A[0][kb], bv, acc[0], 0, 0, 0);
    acc[1] = __builtin_amdgcn_mfma_f32_16x16x32_bf16(A[1][kb], bv, acc[1], 0, 0, 0);
  }
}

// cvt_pk + ONE b128 store: lane (c,q) of wave w owns contiguous storage
// [32w + 8q .. +7] = [t0r0..t0r3, t1r0..t1r3]. 16B-aligned.
__device__ __forceinline__ void write_tile(short* __restrict__ dst, int wrow,
                                           int T0, int quad, f32x2 a0,
                                           f32x2 a1, f32x2 b0, f32x2 b1) {
  uintx4 u;
  u.x = cvtpk_bf16(a0[0], a0[1]);
  u.y = cvtpk_bf16(a1[0], a1[1]);
  u.z = cvtpk_bf16(b0[0], b0[1]);
  u.w = cvtpk_bf16(b1[0], b1[1]);
  *(uintx4*)(dst + wrow + (T0 >> 1) * 32 + quad * 8) = u;
}

__global__ void __launch_bounds__(NTHR, 4)
arima_r19(const float* __restrict__ series,
          const float* __restrict__ rand_error, const float* __restrict__ W1,
          const float* __restrict__ b1, const float* __restrict__ W2,
          const float* __restrict__ b2, const float* __restrict__ W3,
          const float* __restrict__ b3, const short* __restrict__ Mt,
          const float* __restrict__ sv, float* __restrict__ out) {
  __shared__ __align__(16) short buf1[16 * STR];  // h1 (feat 100 = 1.0)
  __shared__ __align__(16) short buf2[16 * STR];  // x0 / h2 / H2avg

  const int tid = threadIdx.x;
  const int w = tid >> 6, l = tid & 63;
  const int col = l & 15, quad = l >> 4;  // col = channel = data row
  const int b = blockIdx.x;               // WG = one batch
  const int T0 = 2 * w;                   // uniform: wave owns tiles 2w,2w+1
  const int wrow = col * STR;
  const int rbase = wrow + quad * 8;
  const bool fixw = (w == 3 && quad == 1);  // owns feat 100 (storage 104)

  // ---- x0 -> buf2 : feats [x0(97), t0=0, 1, 0...], pi-stored ----
  {
    f32x4 xv[2];
#pragma unroll
    for (int t = 0; t < 2; ++t)
#pragma unroll
      for (int r = 0; r < 4; ++r) {
        int q = (T0 + t) * 16 + quad * 4 + r;
        float f = 0.0f;
        if (q < NQ) f = series[(b * NQ + q) * NC + col];
        else if (q == NQ) f = rand_error[b * NC + col];
        else if (q == QP2) f = 1.0f;  // bias feature (q==97: t0 = 0)
        xv[t][r] = f;
      }
    write_tile(buf2, wrow, T0, quad, LO2(xv[0]), HI2(xv[0]), LO2(xv[1]),
               HI2(xv[1]));
  }
  __syncthreads();

  // ---- z0 = W1'[x0,0,1] ; v = sv - dt*z0 ; h1_0 -> buf1 ----
  f32x4 z[2], v[2];
  {
    bf16x8 a1[2][4];  // transient
#pragma unroll
    for (int t = 0; t < 2; ++t)
      load_afrag(W1, b1, QP2, NH, QP2, (T0 + t) * 16 + col, quad, a1[t]);
    z[0] = splat4(0.0f);
    z[1] = splat4(0.0f);
    gemm_acc(buf2, rbase, a1, z);
#pragma unroll
    for (int t = 0; t < 2; ++t) {
      f32x4 s;
#pragma unroll
      for (int r = 0; r < 4; ++r) s[r] = sv[(T0 + t) * 16 + quad * 4 + r];
      v[t] = s - splat4(0.01f) * z[t];
    }
  }
  {
    f32x2 p0 = LO2(z[0]), p1 = HI2(z[0]), p2 = LO2(z[1]), p3 = HI2(z[1]);
    tanh_pair(p0, p1);
    tanh_pair(p2, p3);
    if (fixw) p0[0] = 1.0f;  // h1 feat 100 = 1.0 (W2 bias input)
    write_tile(buf1, wrow, T0, quad, p0, p1, p2, p3);
  }
  __syncthreads();

  // ---- persistent frags: W2' + dtM (pi-permuted k gather) ----
  bf16x8 a2[2][4], am[2][4];
#pragma unroll
  for (int t = 0; t < 2; ++t) {
    load_afrag(W2, b2, NH, NH, NH, (T0 + t) * 16 + col, quad, a2[t]);
    const short* mrow = Mt + ((T0 + t) * 16 + col) * MT_K;
#pragma unroll
    for (int kb = 0; kb < 4; ++kb) {
      shortx4 lo = *(const shortx4*)(mrow + kb * 32 + quad * 4);
      shortx4 hi = *(const shortx4*)(mrow + kb * 32 + 16 + quad * 4);
      bf16x8 vv;
      vv[0] = lo[0]; vv[1] = lo[1]; vv[2] = lo[2]; vv[3] = lo[3];
      vv[4] = hi[0]; vv[5] = hi[1]; vv[6] = hi[2]; vv[7] = hi[3];
      am[t][kb] = vv;
    }
  }
  f32x2 h2s[2][2];
  h2s[0][0] = splat2(0.0f);
  h2s[0][1] = splat2(0.0f);
  h2s[1][0] = splat2(0.0f);
  h2s[1][1] = splat2(0.0f);

#pragma unroll 1
  for (int step = 0; step < NSTEPS_; ++step) {
    // GEMM 1: h2 = tanh(W2'[h1,1]); store, then accumulate H2sum.
    f32x4 acc[2];
    acc[0] = splat4(0.0f);
    acc[1] = splat4(0.0f);
    gemm_acc(buf1, rbase, a2, acc);
    {
      f32x2 p0 = LO2(acc[0]), p1 = HI2(acc[0]), p2 = LO2(acc[1]),
            p3 = HI2(acc[1]);
      tanh_pair(p0, p1);
      tanh_pair(p2, p3);
      write_tile(buf2, wrow, T0, quad, p0, p1, p2, p3);
      h2s[0][0] = h2s[0][0] + p0;
      h2s[0][1] = h2s[0][1] + p1;
      h2s[1][0] = h2s[1][0] + p2;
      h2s[1][1] = h2s[1][1] + p3;
    }
    __syncthreads();
    // GEMM 2: z += dtM h2 (acc_in = z!), z += v ; h1' = tanh(z) -> buf1
    gemm_acc(buf2, rbase, am, z);
    {
      z[0] = z[0] + v[0];
      z[1] = z[1] + v[1];
      f32x2 q0 = LO2(z[0]), q1 = HI2(z[0]), q2 = LO2(z[1]), q3 = HI2(z[1]);
      tanh_pair(q0, q1);
      tanh_pair(q2, q3);
      if (fixw) q0[0] = 1.0f;
      write_tile(buf1, wrow, T0, quad, q0, q1, q2, q3);
    }
    __syncthreads();
  }

  // ---- out = W3'[dt*H2sum, 1] ----
  {
    f32x2 ha00 = splat2(0.01f) * h2s[0][0];
    f32x2 ha01 = splat2(0.01f) * h2s[0][1];
    f32x2 ha10 = splat2(0.01f) * h2s[1][0];
    f32x2 ha11 = splat2(0.01f) * h2s[1][1];
    if (fixw) ha00[0] = 1.0f;  // bias feature for b3
    write_tile(buf2, wrow, T0, quad, ha00, ha01, ha10, ha11);
  }
  __syncthreads();
  {
    bf16x8 a3[2][4];
#pragma unroll
    for (int t = 0; t < 2; ++t)
      load_afrag(W3, b3, NH, QP1, NH, (T0 + t) * 16 + col, quad, a3[t]);
    f32x4 o[2];
    o[0] = splat4(0.0f);
    o[1] = splat4(0.0f);
    gemm_acc(buf2, rbase, a3, o);
#pragma unroll
    for (int t = 0; t < 2; ++t)
#pragma unroll
      for (int r = 0; r < 4; ++r) {
        int q = (T0 + t) * 16 + quad * 4 + r;
        if (q < QP1) out[(b * QP1 + q) * NC + col] = o[t][r];
      }
  }
}

extern "C" void kernel_launch(void* const* d_in, const int* in_sizes, int n_in,
                              void* d_out, int out_size, void* d_ws,
                              size_t ws_size, hipStream_t stream) {
  const float* series = (const float*)d_in[0];
  const float* rand_error = (const float*)d_in[1];
  const float* W1 = (const float*)d_in[2];
  const float* b1 = (const float*)d_in[3];
  const float* W2 = (const float*)d_in[4];
  const float* b2 = (const float*)d_in[5];
  const float* W3 = (const float*)d_in[6];
  const float* b3 = (const float*)d_in[7];
  float* out = (float*)d_out;

  short* Mt = (short*)d_ws;                             // 128*128*2 = 32768 B
  float* sv = (float*)((char*)d_ws + MT_K * MT_K * 2);  // 128 f32

  hipLaunchKernelGGL(arima_prep, dim3(128), dim3(512), 0, stream, W1, b1, W3,
                     b3, Mt, sv);
  hipLaunchKernelGGL(arima_r19, dim3(NB), dim3(NTHR), 0, stream, series,
                     rand_error, W1, b1, W2, b2, W3, b3, Mt, sv, out);
}

// Round 7
// 240.842 us; speedup vs baseline: 1.1026x; 1.0605x over previous
//
#include <hip/hip_runtime.h>

// ARIMA flow sampling, R20 = R19 + exp2-based tanh (VALU -> TRANS offload).
// Post-mortem R19: pi-layout halved write conflicts (1.99e7 -> 1.32e7,
// mechanism confirmed) but time NEUTRAL -> conflicts weren't critical-path.
// Pipe model per SIMD-step (wall 4956cy): VALU 2577 (52%) + MFMA 1242 at
// measured ceiling rate (25%) + LDS ~610 (12%) = 89% of shared issue/pipe
// capacity -> issue-mix bound. Only lever: remove work from dominant pipe.
// tanh Pade(5,4) = 9 VALU + 1 TRANS per element (x16/thread/step, pk can't
// help: f32 pk is half-rate on SIMD-32 -> R15 null). Replace with
//   tanh(x) = 1 - 2/(exp2(2*log2e*x)+1)   [3 VALU + 2 TRANS, no clamp:
// result provably in [-1,1], saturates exactly via inf/0; MORE accurate
// than Pade in tails]. TRANS pipe ~10% busy, overlaps across waves.
// Predicted: VALUBusy 52 -> ~40, main 206.5 -> 170-185us, MfmaUtil -> ~27,
// BANK_CONFLICT flat 1.32e7, absmax ~0.0078 (+-1 bf16 ulp, favorable dir).
// Neutral => serial barrier-chain floor; next lever = 1-barrier/step or done.
//
// Algebra (unchanged):
//   z_s := W1'[x_s, t_s, 1]  (L1 preact, fp32 in MFMA accumulators)
//   h1 = tanh(z); h2 = tanh(W2'[h1,1])           (GEMM 1)
//   z += dtM @ h2 + v        dtM = dt*W1x@W3     (GEMM 2, acc_in = z)
//   x_100 = W3'[dt*sum_s h2_s, 1]                (x_0 cancels: 100*dt == 1)
// v = sv - dt*z_0 per-row in regs; t folded into v; biases as input feats.
// pi storage: position p = 32w + 8q + 4t + r holds feature
// f(p) = 32*(p>>5) + 16*((p>>2)&1) + 4*((p>>3)&3) + (p&3).

#define NB 1024
#define NQ 96
#define NC 16
#define NH 100
#define QP1 97
#define QP2 98
#define NTHR 256
#define STR 136
#define NSTEPS_ 100
#define MT_K 128  // dtM row stride (bf16)

typedef __attribute__((ext_vector_type(8))) short bf16x8;
typedef __attribute__((ext_vector_type(4))) short shortx4;
typedef __attribute__((ext_vector_type(4))) float f32x4;
typedef __attribute__((ext_vector_type(2))) float f32x2;
typedef __attribute__((ext_vector_type(4))) unsigned uintx4;

#define LO2(v) __builtin_shufflevector(v, v, 0, 1)
#define HI2(v) __builtin_shufflevector(v, v, 2, 3)

__device__ __forceinline__ f32x4 splat4(float f) {
  f32x4 v = f;
  return v;
}

__device__ __forceinline__ f32x2 splat2(float f) {
  f32x2 v = f;
  return v;
}

__device__ __forceinline__ short f2bf_rne(float f) {  // one-time paths only
  unsigned u = __builtin_bit_cast(unsigned, f);
  u = u + 0x7fffu + ((u >> 16) & 1u);
  return (short)(u >> 16);
}

// 2 floats -> packed bf16x2 dword, RNE, single instruction.
__device__ __forceinline__ unsigned cvtpk_bf16(float a, float b) {
  unsigned r;
  asm("v_cvt_pk_bf16_f32 %0, %1, %2" : "=v"(r) : "v"(a), "v"(b));
  return r;
}

// hardware exp2 (v_exp_f32)
#if __has_builtin(__builtin_amdgcn_exp2f)
__device__ __forceinline__ float hexp2(float x) {
  return __builtin_amdgcn_exp2f(x);
}
#else
__device__ __forceinline__ float hexp2(float x) {
  float r;
  asm("v_exp_f32 %0, %1\n\ts_nop 1" : "=v"(r) : "v"(x));
  return r;
}
#endif

// tanh(x) = 1 - 2/(e^(2x)+1) = 1 - 2*rcp(exp2(C*x)+1), C = 2*log2(e).
// 3 VALU + 2 TRANS per element; result in [-1,1] by construction
// (t>=0 -> rcp(t+1) in [0,1]); saturates exactly at +-1 via inf/0.
__device__ __forceinline__ float tanh1(float x) {
  float t = hexp2(x * 2.885390081777927f);
  float r = __builtin_amdgcn_rcpf(t + 1.0f);
  return fmaf(-2.0f, r, 1.0f);
}

__device__ __forceinline__ void tanh_pair(f32x2& p, f32x2& q) {
  p[0] = tanh1(p[0]);
  p[1] = tanh1(p[1]);
  q[0] = tanh1(q[0]);
  q[1] = tanh1(q[1]);
}

// ---------------- prep: dtM = dt * W1x @ W3 (bf16) + s-vec ----------------
// grid 128 (= n), block 512 (k = tid&127, jslice = tid>>7); LDS reduce.
// Mt stays in ORIGINAL k order; pi applied at am-fragment fill in main.
__global__ void __launch_bounds__(512) arima_prep(
    const float* __restrict__ W1, const float* __restrict__ b1,
    const float* __restrict__ W3, const float* __restrict__ b3,
    short* __restrict__ Mt, float* __restrict__ sv) {
  __shared__ float part[4][128];
  __shared__ float pb[128];
  const int n = blockIdx.x;
  const int tid = threadIdx.x;
  const int k = tid & 127, js = tid >> 7;
  float s = 0.0f;
  if (n < NH && k < NH) {
    int j0 = js * 25, j1 = (js == 3) ? QP1 : j0 + 25;
    for (int j = j0; j < j1; ++j)
      s = fmaf(W1[n * QP2 + j], W3[j * NH + k], s);
  }
  part[js][k] = s;
  if (tid < 128)
    pb[tid] = (tid < QP1 && n < NH) ? W1[n * QP2 + tid] * b3[tid] : 0.0f;
  __syncthreads();
  if (js == 0) {
    float tot = part[0][k] + part[1][k] + part[2][k] + part[3][k];
    Mt[n * MT_K + k] = f2bf_rne(0.01f * tot);
  }
  if (tid == 0) {
    float d = 0.0f;
    for (int j = 0; j < 128; ++j) d += pb[j];
    sv[n] = (n < NH) ? 0.01f * (d + b1[n] + W1[n * QP2 + QP1]) : 0.0f;
  }
}

// ---------------- main ----------------
// Weight A-frag from fp32 W, pi-permuted k columns:
// frag slot (kb, i) holds W column kcol = kb*32 + 16*(i>>2) + quad*4 + (i&3).
__device__ void load_afrag(const float* __restrict__ W,
                           const float* __restrict__ bias, int ws, int mvalid,
                           int KW, int m, int quad, bf16x8 dst[4]) {
#pragma unroll
  for (int kb = 0; kb < 4; ++kb) {
    bf16x8 v;
#pragma unroll
    for (int i = 0; i < 8; ++i) {
      int kcol = kb * 32 + ((i >> 2) << 4) + quad * 4 + (i & 3);
      float f = 0.0f;
      if (m < mvalid) {
        if (kcol < KW) f = W[m * ws + kcol];
        else if (kcol == KW) f = bias[m];
      }
      v[i] = f2bf_rne(f);
    }
    dst[kb] = v;
  }
}

// acc += A * B(LDS). 2 tiles, K=128 (4 kb). acc carries in (z-update!).
// Read code identical to R15; k index is now storage (pi) order.
__device__ __forceinline__ void gemm_acc(const short* __restrict__ src,
                                         int rbase, const bf16x8 (&A)[2][4],
                                         f32x4 (&acc)[2]) {
#pragma unroll
  for (int kb = 0; kb < 4; ++kb) {
    bf16x8 bv = *(const bf16x8*)(src + rbase + kb * 32);  // 16B aligned
    acc[0] = __builtin_amdgcn_mfma_f32_16x16x32_bf16(A[0][kb], bv, acc[0], 0, 0, 0);
    acc[1] = __builtin_amdgcn_mfma_f32_16x16x32_bf16(A[1][kb], bv, acc[1], 0, 0, 0);
  }
}

// cvt_pk + ONE b128 store: lane (c,q) of wave w owns contiguous storage
// [32w + 8q .. +7] = [t0r0..t0r3, t1r0..t1r3]. 16B-aligned.
__device__ __forceinline__ void write_tile(short* __restrict__ dst, int wrow,
                                           int T0, int quad, f32x2 a0,
                                           f32x2 a1, f32x2 b0, f32x2 b1) {
  uintx4 u;
  u.x = cvtpk_bf16(a0[0], a0[1]);
  u.y = cvtpk_bf16(a1[0], a1[1]);
  u.z = cvtpk_bf16(b0[0], b0[1]);
  u.w = cvtpk_bf16(b1[0], b1[1]);
  *(uintx4*)(dst + wrow + (T0 >> 1) * 32 + quad * 8) = u;
}

__global__ void __launch_bounds__(NTHR, 4)
arima_r20(const float* __restrict__ series,
          const float* __restrict__ rand_error, const float* __restrict__ W1,
          const float* __restrict__ b1, const float* __restrict__ W2,
          const float* __restrict__ b2, const float* __restrict__ W3,
          const float* __restrict__ b3, const short* __restrict__ Mt,
          const float* __restrict__ sv, float* __restrict__ out) {
  __shared__ __align__(16) short buf1[16 * STR];  // h1 (feat 100 = 1.0)
  __shared__ __align__(16) short buf2[16 * STR];  // x0 / h2 / H2avg

  const int tid = threadIdx.x;
  const int w = tid >> 6, l = tid & 63;
  const int col = l & 15, quad = l >> 4;  // col = channel = data row
  const int b = blockIdx.x;               // WG = one batch
  const int T0 = 2 * w;                   // uniform: wave owns tiles 2w,2w+1
  const int wrow = col * STR;
  const int rbase = wrow + quad * 8;
  const bool fixw = (w == 3 && quad == 1);  // owns feat 100 (storage 104)

  // ---- x0 -> buf2 : feats [x0(97), t0=0, 1, 0...], pi-stored ----
  {
    f32x4 xv[2];
#pragma unroll
    for (int t = 0; t < 2; ++t)
#pragma unroll
      for (int r = 0; r < 4; ++r) {
        int q = (T0 + t) * 16 + quad * 4 + r;
        float f = 0.0f;
        if (q < NQ) f = series[(b * NQ + q) * NC + col];
        else if (q == NQ) f = rand_error[b * NC + col];
        else if (q == QP2) f = 1.0f;  // bias feature (q==97: t0 = 0)
        xv[t][r] = f;
      }
    write_tile(buf2, wrow, T0, quad, LO2(xv[0]), HI2(xv[0]), LO2(xv[1]),
               HI2(xv[1]));
  }
  __syncthreads();

  // ---- z0 = W1'[x0,0,1] ; v = sv - dt*z0 ; h1_0 -> buf1 ----
  f32x4 z[2], v[2];
  {
    bf16x8 a1[2][4];  // transient
#pragma unroll
    for (int t = 0; t < 2; ++t)
      load_afrag(W1, b1, QP2, NH, QP2, (T0 + t) * 16 + col, quad, a1[t]);
    z[0] = splat4(0.0f);
    z[1] = splat4(0.0f);
    gemm_acc(buf2, rbase, a1, z);
#pragma unroll
    for (int t = 0; t < 2; ++t) {
      f32x4 s;
#pragma unroll
      for (int r = 0; r < 4; ++r) s[r] = sv[(T0 + t) * 16 + quad * 4 + r];
      v[t] = s - splat4(0.01f) * z[t];
    }
  }
  {
    f32x2 p0 = LO2(z[0]), p1 = HI2(z[0]), p2 = LO2(z[1]), p3 = HI2(z[1]);
    tanh_pair(p0, p1);
    tanh_pair(p2, p3);
    if (fixw) p0[0] = 1.0f;  // h1 feat 100 = 1.0 (W2 bias input)
    write_tile(buf1, wrow, T0, quad, p0, p1, p2, p3);
  }
  __syncthreads();

  // ---- persistent frags: W2' + dtM (pi-permuted k gather) ----
  bf16x8 a2[2][4], am[2][4];
#pragma unroll
  for (int t = 0; t < 2; ++t) {
    load_afrag(W2, b2, NH, NH, NH, (T0 + t) * 16 + col, quad, a2[t]);
    const short* mrow = Mt + ((T0 + t) * 16 + col) * MT_K;
#pragma unroll
    for (int kb = 0; kb < 4; ++kb) {
      shortx4 lo = *(const shortx4*)(mrow + kb * 32 + quad * 4);
      shortx4 hi = *(const shortx4*)(mrow + kb * 32 + 16 + quad * 4);
      bf16x8 vv;
      vv[0] = lo[0]; vv[1] = lo[1]; vv[2] = lo[2]; vv[3] = lo[3];
      vv[4] = hi[0]; vv[5] = hi[1]; vv[6] = hi[2]; vv[7] = hi[3];
      am[t][kb] = vv;
    }
  }
  f32x2 h2s[2][2];
  h2s[0][0] = splat2(0.0f);
  h2s[0][1] = splat2(0.0f);
  h2s[1][0] = splat2(0.0f);
  h2s[1][1] = splat2(0.0f);

#pragma unroll 1
  for (int step = 0; step < NSTEPS_; ++step) {
    // GEMM 1: h2 = tanh(W2'[h1,1]); store, then accumulate H2sum.
    f32x4 acc[2];
    acc[0] = splat4(0.0f);
    acc[1] = splat4(0.0f);
    gemm_acc(buf1, rbase, a2, acc);
    {
      f32x2 p0 = LO2(acc[0]), p1 = HI2(acc[0]), p2 = LO2(acc[1]),
            p3 = HI2(acc[1]);
      tanh_pair(p0, p1);
      tanh_pair(p2, p3);
      write_tile(buf2, wrow, T0, quad, p0, p1, p2, p3);
      h2s[0][0] = h2s[0][0] + p0;
      h2s[0][1] = h2s[0][1] + p1;
      h2s[1][0] = h2s[1][0] + p2;
      h2s[1][1] = h2s[1][1] + p3;
    }
    __syncthreads();
    // GEMM 2: z += dtM h2 (acc_in = z!), z += v ; h1' = tanh(z) -> buf1
    gemm_acc(buf2, rbase, am, z);
    {
      z[0] = z[0] + v[0];
      z[1] = z[1] + v[1];
      f32x2 q0 = LO2(z[0]), q1 = HI2(z[0]), q2 = LO2(z[1]), q3 = HI2(z[1]);
      tanh_pair(q0, q1);
      tanh_pair(q2, q3);
      if (fixw) q0[0] = 1.0f;
      write_tile(buf1, wrow, T0, quad, q0, q1, q2, q3);
    }
    __syncthreads();
  }

  // ---- out = W3'[dt*H2sum, 1] ----
  {
    f32x2 ha00 = splat2(0.01f) * h2s[0][0];
    f32x2 ha01 = splat2(0.01f) * h2s[0][1];
    f32x2 ha10 = splat2(0.01f) * h2s[1][0];
    f32x2 ha11 = splat2(0.01f) * h2s[1][1];
    if (fixw) ha00[0] = 1.0f;  // bias feature for b3
    write_tile(buf2, wrow, T0, quad, ha00, ha01, ha10, ha11);
  }
  __syncthreads();
  {
    bf16x8 a3[2][4];
#pragma unroll
    for (int t = 0; t < 2; ++t)
      load_afrag(W3, b3, NH, QP1, NH, (T0 + t) * 16 + col, quad, a3[t]);
    f32x4 o[2];
    o[0] = splat4(0.0f);
    o[1] = splat4(0.0f);
    gemm_acc(buf2, rbase, a3, o);
#pragma unroll
    for (int t = 0; t < 2; ++t)
#pragma unroll
      for (int r = 0; r < 4; ++r) {
        int q = (T0 + t) * 16 + quad * 4 + r;
        if (q < QP1) out[(b * QP1 + q) * NC + col] = o[t][r];
      }
  }
}

extern "C" void kernel_launch(void* const* d_in, const int* in_sizes, int n_in,
                              void* d_out, int out_size, void* d_ws,
                              size_t ws_size, hipStream_t stream) {
  const float* series = (const float*)d_in[0];
  const float* rand_error = (const float*)d_in[1];
  const float* W1 = (const float*)d_in[2];
  const float* b1 = (const float*)d_in[3];
  const float* W2 = (const float*)d_in[4];
  const float* b2 = (const float*)d_in[5];
  const float* W3 = (const float*)d_in[6];
  const float* b3 = (const float*)d_in[7];
  float* out = (float*)d_out;

  short* Mt = (short*)d_ws;                             // 128*128*2 = 32768 B
  float* sv = (float*)((char*)d_ws + MT_K * MT_K * 2);  // 128 f32

  hipLaunchKernelGGL(arima_prep, dim3(128), dim3(512), 0, stream, W1, b1, W3,
                     b3, Mt, sv);
  hipLaunchKernelGGL(arima_r20, dim3(NB), dim3(NTHR), 0, stream, series,
                     rand_error, W1, b1, W2, b2, W3, b3, Mt, sv, out);
}